// Round 8
// baseline (446.655 us; speedup 1.0000x reference)
//
#include <hip/hip_runtime.h>
#include <cstdint>
#include <cstddef>

// Problem constants (B=2, L=2048, D=1024, E=8, F=2048, TOP_K=2)
constexpr int T_TOK = 4096;      // B*L
constexpr int D_DIM = 1024;
constexpr int E_NUM = 8;
constexpr int F_DIM = 2048;
constexpr int C2F   = 4096;      // 2*F
constexpr int NPAIR = T_TOK * 2; // 8192 (token, slot) pairs

#define ALPHA_SW 1.702f
#define LIMIT_SW 9.0f

// ---------------- workspace layout (bytes) ----------------
constexpr size_t OFF_OFFSETS = 0;     // int[9]
constexpr size_t OFF_SEL     = 128;
constexpr size_t OFF_WTS     = OFF_SEL    + (size_t)NPAIR * 4;
constexpr size_t OFF_POSOF   = OFF_WTS    + (size_t)NPAIR * 4;
constexpr size_t OFF_FACT    = 131328;                           // f_act bf16 [8192][2048]
constexpr size_t SZ_FACT     = (size_t)NPAIR * F_DIM * 2;        // 33.55 MB
constexpr size_t OFF_XG      = OFF_FACT + SZ_FACT;               // xg bf16 [8192][1024]
constexpr size_t SZ_XG       = (size_t)NPAIR * D_DIM * 2;        // 16.78 MB
constexpr size_t OFF_WB      = OFF_XG + SZ_XG;                   // w1b bf16 (67.1MB); later w2b(33.5)+y16
constexpr size_t SZ_W2B      = (size_t)E_NUM * D_DIM * F_DIM * 2;// 33.55 MB
constexpr size_t OFF_Y       = OFF_WB + SZ_W2B;                  // y bf16 [8192][1024] (16.8MB), overlays w1b tail
// end = OFF_WB + 67.1 MB = 117.5 MB — proven available (R2/R4/R6/R7 ran this footprint)

typedef __bf16 bf16x8 __attribute__((ext_vector_type(8)));
typedef float  f32x16 __attribute__((ext_vector_type(16)));

// round-half-up f32->bf16
__device__ __forceinline__ uint16_t bf16h(float f) {
  return (uint16_t)((__float_as_uint(f) + 0x8000u) >> 16);
}
__device__ __forceinline__ float bf2f(uint32_t h) {
  return __uint_as_float(h << 16);
}
__device__ __forceinline__ uint32_t pack2(float lo, float hi) {
  uint32_t ua = __float_as_uint(lo) + 0x8000u;
  uint32_t ub = __float_as_uint(hi) + 0x8000u;
  return __builtin_amdgcn_perm(ub, ua, 0x07060302); // {ub.hi16, ua.hi16}
}

// async global -> LDS, 16B/lane; dest = wave-uniform base + lane*16
__device__ __forceinline__ void gld_lds16(const uint16_t* g, uint16_t* l) {
  __builtin_amdgcn_global_load_lds(
      (const __attribute__((address_space(1))) unsigned int*)g,
      (__attribute__((address_space(3))) unsigned int*)l,
      16, 0, 0);
}

// fast swiglu (proven R5-R7: absmax unchanged at 0.03125)
__device__ __forceinline__ float swiglu_f(float g, float v) {
  g = fminf(g, LIMIT_SW);
  v = fminf(fmaxf(v, -LIMIT_SW), LIMIT_SW);
  float ex = __expf(-ALPHA_SW * g);
  return g * __builtin_amdgcn_rcpf(1.0f + ex) * (v + 1.0f);
}

// ---------------- K1: gate + top-2 + softmax (NO atomics; R7-proven) ----------------
__global__ __launch_bounds__(256) void gate_route_kernel(
    const float* __restrict__ x, const float* __restrict__ gate_w,
    int* __restrict__ sel, float* __restrict__ wts) {
  const int t = blockIdx.x;
  const int tid = threadIdx.x;
  const int lane = tid & 63, wv = tid >> 6;

  __shared__ double red[4][E_NUM];

  float4 xv = *(const float4*)&x[(size_t)t * D_DIM + tid * 4];
  const float* gw = gate_w + (size_t)tid * 4 * E_NUM;
  float4 g0a = *(const float4*)(gw + 0),  g0b = *(const float4*)(gw + 4);
  float4 g1a = *(const float4*)(gw + 8),  g1b = *(const float4*)(gw + 12);
  float4 g2a = *(const float4*)(gw + 16), g2b = *(const float4*)(gw + 20);
  float4 g3a = *(const float4*)(gw + 24), g3b = *(const float4*)(gw + 28);

  double acc[E_NUM];
  double x0 = xv.x, x1 = xv.y, x2 = xv.z, x3 = xv.w;
  acc[0] = x0*(double)g0a.x + x1*(double)g1a.x + x2*(double)g2a.x + x3*(double)g3a.x;
  acc[1] = x0*(double)g0a.y + x1*(double)g1a.y + x2*(double)g2a.y + x3*(double)g3a.y;
  acc[2] = x0*(double)g0a.z + x1*(double)g1a.z + x2*(double)g2a.z + x3*(double)g3a.z;
  acc[3] = x0*(double)g0a.w + x1*(double)g1a.w + x2*(double)g2a.w + x3*(double)g3a.w;
  acc[4] = x0*(double)g0b.x + x1*(double)g1b.x + x2*(double)g2b.x + x3*(double)g3b.x;
  acc[5] = x0*(double)g0b.y + x1*(double)g1b.y + x2*(double)g2b.y + x3*(double)g3b.y;
  acc[6] = x0*(double)g0b.z + x1*(double)g1b.z + x2*(double)g2b.z + x3*(double)g3b.z;
  acc[7] = x0*(double)g0b.w + x1*(double)g1b.w + x2*(double)g2b.w + x3*(double)g3b.w;

#pragma unroll
  for (int off = 32; off >= 1; off >>= 1) {
#pragma unroll
    for (int e = 0; e < E_NUM; ++e) acc[e] += __shfl_down(acc[e], off, 64);
  }
  if (lane == 0) {
#pragma unroll
    for (int e = 0; e < E_NUM; ++e) red[wv][e] = acc[e];
  }
  __syncthreads();
  if (tid == 0) {
#pragma unroll
    for (int e = 0; e < E_NUM; ++e)
      acc[e] = red[0][e] + red[1][e] + red[2][e] + red[3][e];
    int b0 = 0;
#pragma unroll
    for (int e = 1; e < E_NUM; ++e)
      if (acc[e] > acc[b0]) b0 = e;
    int b1 = (b0 == 0) ? 1 : 0;
#pragma unroll
    for (int e = 0; e < E_NUM; ++e)
      if (e != b0 && acc[e] > acc[b1] && e != b1) {
        if (e < b1 && acc[e] == acc[b1]) continue;
        if (acc[e] > acc[b1]) b1 = e;
      }
    double p0 = 1.0 / (1.0 + exp(acc[b1] - acc[b0]));
    sel[t * 2 + 0] = b0;
    sel[t * 2 + 1] = b1;
    wts[t * 2 + 0] = (float)p0;
    wts[t * 2 + 1] = (float)(1.0 - p0);
  }
}

// ---------------- K2: deterministic routing scan (single block; R7-proven) ----------------
__global__ __launch_bounds__(256) void route_scan_kernel(
    const int* __restrict__ sel, int* __restrict__ pos_of, int* __restrict__ offsets) {
  __shared__ int cnt[256 * E_NUM];   // 8 KB
  __shared__ int tot[E_NUM];
  const int tid = threadIdx.x;

  int4 sv[8];
  const int4* sp = (const int4*)(sel + tid * 32);
#pragma unroll
  for (int j = 0; j < 8; ++j) sv[j] = sp[j];

  int local[E_NUM];
#pragma unroll
  for (int e = 0; e < E_NUM; ++e) local[e] = 0;
#pragma unroll
  for (int j = 0; j < 8; ++j) {
#pragma unroll
    for (int e = 0; e < E_NUM; ++e)
      local[e] += (sv[j].x == e) + (sv[j].y == e) + (sv[j].z == e) + (sv[j].w == e);
  }
#pragma unroll
  for (int e = 0; e < E_NUM; ++e) cnt[tid * E_NUM + e] = local[e];
  __syncthreads();

  if (tid < E_NUM) {
    int s = 0;
    for (int t = 0; t < 256; ++t) {
      int c = cnt[t * E_NUM + tid];
      cnt[t * E_NUM + tid] = s;
      s += c;
    }
    tot[tid] = s;
  }
  __syncthreads();
  if (tid == 0) {
    int s = 0;
    for (int e = 0; e < E_NUM; ++e) {
      int c = tot[e];
      tot[e] = s;
      offsets[e] = s;
      s += c;
    }
    offsets[E_NUM] = s;
  }
  __syncthreads();

#pragma unroll
  for (int e = 0; e < E_NUM; ++e) cnt[tid * E_NUM + e] += tot[e];

#pragma unroll
  for (int j = 0; j < 8; ++j) {
    int p = tid * 32 + j * 4;
    int4 v = sv[j];
    int pos;
    pos = cnt[tid * E_NUM + v.x]++; pos_of[p + 0] = pos;
    pos = cnt[tid * E_NUM + v.y]++; pos_of[p + 1] = pos;
    pos = cnt[tid * E_NUM + v.z]++; pos_of[p + 2] = pos;
    pos = cnt[tid * E_NUM + v.w]++; pos_of[p + 3] = pos;
  }
}

// ---------------- K3: gather x row -> both compacted bf16 copies ----------------
__global__ __launch_bounds__(256) void gather_x_kernel(
    const float* __restrict__ x, const int* __restrict__ pos_of,
    uint16_t* __restrict__ xg) {
  int t = blockIdx.x;
  int d = threadIdx.x * 4;
  float4 v = *(const float4*)&x[(size_t)t * D_DIM + d];
  uint2 o;
  o.x = pack2(v.x, v.y);
  o.y = pack2(v.z, v.w);
  int i0 = pos_of[2 * t], i1 = pos_of[2 * t + 1];
  *(uint2*)&xg[(size_t)i0 * D_DIM + d] = o;
  *(uint2*)&xg[(size_t)i1 * D_DIM + d] = o;
}

// ---------------- K4: w1 cvt + g/v 64-group de-interleave ----------------
// Out col group of 64: first 32 rows = g of f=32q+s, next 32 = v of f=32q+s.
// c_in: g -> 64q + 2s ; v -> 64q + 2s + 1.
__global__ __launch_bounds__(256) void cvt_w1_kernel(
    const float* __restrict__ w1, uint16_t* __restrict__ w1b) {
  int row = blockIdx.x;            // e*4096 + c_out
  int c_out = row & (C2F - 1);
  int e = row >> 12;
  int q = c_out >> 6, s = c_out & 63;
  int c_in = (q << 6) + ((s < 32) ? (s << 1) : (((s - 32) << 1) | 1));
  const float* src = w1 + ((size_t)e * C2F + c_in) * D_DIM + threadIdx.x * 4;
  float4 v = *(const float4*)src;
  uint2 o;
  o.x = pack2(v.x, v.y);
  o.y = pack2(v.z, v.w);
  *(uint2*)&w1b[(size_t)row * D_DIM + threadIdx.x * 4] = o;
}

// ---------------- K5: plain f32 -> bf16 convert (w2) ----------------
__global__ __launch_bounds__(256) void cvt_bf16_kernel(
    const float* __restrict__ src, uint16_t* __restrict__ dst, int n4) {
  int i = blockIdx.x * 256 + threadIdx.x;
  if (i >= n4) return;
  float4 v = ((const float4*)src)[i];
  uint2 o;
  o.x = pack2(v.x, v.y);
  o.y = pack2(v.z, v.w);
  ((uint2*)dst)[i] = o;
}

// LDS tile: 128 rows x 64 bf16 (BK=64); row = 128B = 8 chunks of 16B.
// Swizzle: slot s of row r holds k-chunk s ^ (r&7) — conflict-free (R5-R7 verified).
// 32x32x16 MFMA fragments: A row = lane&31, k-chunk = lane>>5 (m74/m101 layouts);
// C/D: col = lane&31, row = (reg&3) + 8*(reg>>2) + 4*(lane>>5).

// ---------------- K6: GEMM1  f_act = swiglu(xg @ w1b^T + b1), 32x32x16 MFMA ----------------
__global__ __launch_bounds__(256) void gemm1_kernel(
    const uint16_t* __restrict__ xg, const uint16_t* __restrict__ w1b,
    const float* __restrict__ b1, const int* __restrict__ offsets,
    uint16_t* __restrict__ f_act) {
  const int e = blockIdx.z;
  const int base = offsets[e];
  const int n_e = offsets[e + 1] - base;
  const int row0 = blockIdx.y * 128;
  if (row0 >= n_e) return;
  const int c0 = blockIdx.x * 128;

  __shared__ uint16_t As[128 * 64];   // 16 KB
  __shared__ uint16_t Bs[128 * 64];   // 16 KB

  const int tid = threadIdx.x;
  const int lane = tid & 63;
  const int wv = tid >> 6;
  const int wm = wv & 1, wn = wv >> 1;

  // staging (unchanged from R7): 8 gld_lds16 per wave per k-tile
  const int srow = lane >> 3;
  const int schunk = ((lane & 7) ^ srow) * 8;
  const uint16_t* agp[4]; uint16_t* alds[4];
  const uint16_t* bgp[4]; uint16_t* blds[4];
#pragma unroll
  for (int j = 0; j < 4; ++j) {
    int tr = wv * 32 + 8 * j + srow;
    int ag = base + row0 + tr; if (ag > NPAIR - 1) ag = NPAIR - 1;
    agp[j] = xg + (size_t)ag * D_DIM + schunk;
    alds[j] = &As[(wv * 32 + 8 * j) * 64];
    bgp[j] = w1b + ((size_t)e * C2F + c0 + tr) * D_DIM + schunk;
    blds[j] = &Bs[(wv * 32 + 8 * j) * 64];
  }

  f32x16 acc[2][2];
#pragma unroll
  for (int mt = 0; mt < 2; ++mt)
#pragma unroll
    for (int nt = 0; nt < 2; ++nt)
#pragma unroll
      for (int r = 0; r < 16; ++r) acc[mt][nt][r] = 0.f;

  const int l31 = lane & 31;
  const int kh = lane >> 5;            // k-chunk half (0/1)
  const int sx = lane & 7;             // swizzle xor term (row&7 == lane&7)
  const uint16_t* Arow = &As[(wm * 64 + l31) * 64];
  const uint16_t* Brow = &Bs[(wn * 64 + l31) * 64];

#pragma unroll
  for (int kt = 0; kt < D_DIM / 64; ++kt) {
    __syncthreads();
#pragma unroll
    for (int j = 0; j < 4; ++j) gld_lds16(agp[j] + kt * 64, alds[j]);
#pragma unroll
    for (int j = 0; j < 4; ++j) gld_lds16(bgp[j] + kt * 64, blds[j]);
    __syncthreads();

#pragma unroll
    for (int ks = 0; ks < 4; ++ks) {   // 4 k16-steps per k64-tile
      int slot = ((ks * 2 + kh) ^ sx) * 8;
      bf16x8 a0 = *(const bf16x8*)(Arow + slot);
      bf16x8 a1 = *(const bf16x8*)(Arow + 32 * 64 + slot);
      bf16x8 b0 = *(const bf16x8*)(Brow + slot);
      bf16x8 b1v = *(const bf16x8*)(Brow + 32 * 64 + slot);
      acc[0][0] = __builtin_amdgcn_mfma_f32_32x32x16_bf16(a0, b0,  acc[0][0], 0, 0, 0);
      acc[0][1] = __builtin_amdgcn_mfma_f32_32x32x16_bf16(a0, b1v, acc[0][1], 0, 0, 0);
      acc[1][0] = __builtin_amdgcn_mfma_f32_32x32x16_bf16(a1, b0,  acc[1][0], 0, 0, 0);
      acc[1][1] = __builtin_amdgcn_mfma_f32_32x32x16_bf16(a1, b1v, acc[1][1], 0, 0, 0);
    }
  }

  // epilogue: nt=0 tile holds g, nt=1 holds v for the same f (same lane/reg)
  const float* b1e = b1 + (size_t)e * C2F;
  const int gbase = c0 + wn * 64;
  const float bg = b1e[gbase + 2 * l31];
  const float bv = b1e[gbase + 2 * l31 + 1];
  const int fcol = (gbase >> 1) + l31;
  const int rbase = 4 * kh;
#pragma unroll
  for (int mt = 0; mt < 2; ++mt)
#pragma unroll
    for (int r = 0; r < 16; ++r) {
      int row_l = wm * 64 + mt * 32 + rbase + (r & 3) + 8 * (r >> 2);
      if (row0 + row_l < n_e) {
        float g = acc[mt][0][r] + bg;
        float v = acc[mt][1][r] + bv;
        f_act[(size_t)(base + row0 + row_l) * F_DIM + fcol] = bf16h(swiglu_f(g, v));
      }
    }
}

// ---------------- K7: GEMM2  y16 = f_act @ w2b^T + b2  (bf16 stores), 32x32x16 MFMA ----------------
__global__ __launch_bounds__(256) void gemm2_kernel(
    const uint16_t* __restrict__ f_act, const uint16_t* __restrict__ w2b,
    const float* __restrict__ b2, const int* __restrict__ offsets,
    uint16_t* __restrict__ y16) {
  const int e = blockIdx.z;
  const int base = offsets[e];
  const int n_e = offsets[e + 1] - base;
  const int row0 = blockIdx.y * 128;
  if (row0 >= n_e) return;
  const int c0 = blockIdx.x * 128;

  __shared__ uint16_t As[128 * 64];
  __shared__ uint16_t Bs[128 * 64];

  const int tid = threadIdx.x;
  const int lane = tid & 63;
  const int wv = tid >> 6;
  const int wm = wv & 1, wn = wv >> 1;

  const int srow = lane >> 3;
  const int schunk = ((lane & 7) ^ srow) * 8;
  const uint16_t* agp[4]; uint16_t* alds[4];
  const uint16_t* bgp[4]; uint16_t* blds[4];
#pragma unroll
  for (int j = 0; j < 4; ++j) {
    int tr = wv * 32 + 8 * j + srow;
    int ag = base + row0 + tr; if (ag > NPAIR - 1) ag = NPAIR - 1;
    agp[j] = f_act + (size_t)ag * F_DIM + schunk;
    alds[j] = &As[(wv * 32 + 8 * j) * 64];
    bgp[j] = w2b + ((size_t)e * D_DIM + c0 + tr) * F_DIM + schunk;
    blds[j] = &Bs[(wv * 32 + 8 * j) * 64];
  }

  f32x16 acc[2][2];
#pragma unroll
  for (int mt = 0; mt < 2; ++mt)
#pragma unroll
    for (int nt = 0; nt < 2; ++nt)
#pragma unroll
      for (int r = 0; r < 16; ++r) acc[mt][nt][r] = 0.f;

  const int l31 = lane & 31;
  const int kh = lane >> 5;
  const int sx = lane & 7;
  const uint16_t* Arow = &As[(wm * 64 + l31) * 64];
  const uint16_t* Brow = &Bs[(wn * 64 + l31) * 64];

#pragma unroll
  for (int kt = 0; kt < F_DIM / 64; ++kt) {
    __syncthreads();
#pragma unroll
    for (int j = 0; j < 4; ++j) gld_lds16(agp[j] + kt * 64, alds[j]);
#pragma unroll
    for (int j = 0; j < 4; ++j) gld_lds16(bgp[j] + kt * 64, blds[j]);
    __syncthreads();

#pragma unroll
    for (int ks = 0; ks < 4; ++ks) {
      int slot = ((ks * 2 + kh) ^ sx) * 8;
      bf16x8 a0 = *(const bf16x8*)(Arow + slot);
      bf16x8 a1 = *(const bf16x8*)(Arow + 32 * 64 + slot);
      bf16x8 b0 = *(const bf16x8*)(Brow + slot);
      bf16x8 b1v = *(const bf16x8*)(Brow + 32 * 64 + slot);
      acc[0][0] = __builtin_amdgcn_mfma_f32_32x32x16_bf16(a0, b0,  acc[0][0], 0, 0, 0);
      acc[0][1] = __builtin_amdgcn_mfma_f32_32x32x16_bf16(a0, b1v, acc[0][1], 0, 0, 0);
      acc[1][0] = __builtin_amdgcn_mfma_f32_32x32x16_bf16(a1, b0,  acc[1][0], 0, 0, 0);
      acc[1][1] = __builtin_amdgcn_mfma_f32_32x32x16_bf16(a1, b1v, acc[1][1], 0, 0, 0);
    }
  }

  // epilogue: bias + bf16 stores into compacted y
  const int col0 = c0 + wn * 64 + l31;
  const float bias0 = b2[(size_t)e * D_DIM + col0];
  const float bias1 = b2[(size_t)e * D_DIM + col0 + 32];
  const int rbase = 4 * kh;
#pragma unroll
  for (int mt = 0; mt < 2; ++mt)
#pragma unroll
    for (int r = 0; r < 16; ++r) {
      int row_l = wm * 64 + mt * 32 + rbase + (r & 3) + 8 * (r >> 2);
      if (row0 + row_l < n_e) {
        size_t yb = (size_t)(base + row0 + row_l) * D_DIM;
        y16[yb + col0]      = bf16h(acc[mt][0][r] + bias0);
        y16[yb + col0 + 32] = bf16h(acc[mt][1][r] + bias1);
      }
    }
}

// ---------------- K8: combine the two expert outputs per token (bf16 y) ----------------
__global__ __launch_bounds__(256) void combine_kernel(
    const uint16_t* __restrict__ y16, const int* __restrict__ pos_of,
    const float* __restrict__ wts, float* __restrict__ out) {
  int t = blockIdx.x;
  int d4 = threadIdx.x * 4;
  int p0 = pos_of[t * 2], p1 = pos_of[t * 2 + 1];
  float w0 = wts[t * 2], w1v = wts[t * 2 + 1];
  uint2 a = *(const uint2*)&y16[(size_t)p0 * D_DIM + d4];
  uint2 b = *(const uint2*)&y16[(size_t)p1 * D_DIM + d4];
  float4 o;
  o.x = w0 * bf2f(a.x & 0xffffu) + w1v * bf2f(b.x & 0xffffu);
  o.y = w0 * bf2f(a.x >> 16)     + w1v * bf2f(b.x >> 16);
  o.z = w0 * bf2f(a.y & 0xffffu) + w1v * bf2f(b.y & 0xffffu);
  o.w = w0 * bf2f(a.y >> 16)     + w1v * bf2f(b.y >> 16);
  *(float4*)&out[(size_t)t * D_DIM + d4] = o;
}

extern "C" void kernel_launch(void* const* d_in, const int* in_sizes, int n_in,
                              void* d_out, int out_size, void* d_ws, size_t ws_size,
                              hipStream_t stream) {
  const float* x      = (const float*)d_in[0];
  const float* gate_w = (const float*)d_in[1];
  const float* w1     = (const float*)d_in[2];
  const float* b1     = (const float*)d_in[3];
  const float* w2     = (const float*)d_in[4];
  const float* b2     = (const float*)d_in[5];
  float* out = (float*)d_out;

  char* ws = (char*)d_ws;
  int*      offsets = (int*)(ws + OFF_OFFSETS);
  int*      sel     = (int*)(ws + OFF_SEL);
  float*    wts     = (float*)(ws + OFF_WTS);
  int*      pos_of  = (int*)(ws + OFF_POSOF);
  uint16_t* f_act   = (uint16_t*)(ws + OFF_FACT);
  uint16_t* xg      = (uint16_t*)(ws + OFF_XG);
  uint16_t* w1b     = (uint16_t*)(ws + OFF_WB);
  uint16_t* w2b     = (uint16_t*)(ws + OFF_WB);   // reuses w1b region after gemm1
  uint16_t* y16     = (uint16_t*)(ws + OFF_Y);    // overlays w1b tail

  cvt_w1_kernel<<<E_NUM * C2F, 256, 0, stream>>>(w1, w1b);
  gate_route_kernel<<<T_TOK, 256, 0, stream>>>(x, gate_w, sel, wts);
  route_scan_kernel<<<1, 256, 0, stream>>>(sel, pos_of, offsets);
  gather_x_kernel<<<T_TOK, 256, 0, stream>>>(x, pos_of, xg);
  gemm1_kernel<<<dim3(C2F / 128, 64, E_NUM), 256, 0, stream>>>(xg, w1b, b1, offsets, f_act);
  cvt_bf16_kernel<<<(E_NUM * D_DIM * F_DIM / 4) / 256, 256, 0, stream>>>(
      w2, w2b, E_NUM * D_DIM * F_DIM / 4);
  gemm2_kernel<<<dim3(D_DIM / 128, 64, E_NUM), 256, 0, stream>>>(f_act, w2b, b2, offsets, y16);
  combine_kernel<<<T_TOK, 256, 0, stream>>>(y16, pos_of, wts, out);
}